// Round 6
// baseline (324.660 us; speedup 1.0000x reference)
//
#include <hip/hip_runtime.h>

#define B_    32
#define L_    4096
#define DIN   150
#define DST   75
#define HID   75
#define HPAD  80
#define INF30 1e30f

// ---------------- ws layout (floats) ----------------
// W0p[DIN*HPAD] : input-part of W0, h-padded to 80 (12000)
// W1p[HPAD]     : W1 padded (80)
// sp[B_*HPAD]   : state @ W0[:75] + b0, h-padded (2560)
// m[B_], inv[B_]

__global__ void k_zero(float* __restrict__ p, int n) {
    int i = blockIdx.x * 256 + threadIdx.x;
    if (i < n) p[i] = 0.f;
}

// Pad weights: W0p[d][h] = W0[DST+d][h] (h<75 else 0), W1p[h] likewise.
__global__ __launch_bounds__(256) void k_prep(
    const float* __restrict__ W0, const float* __restrict__ W1,
    float* __restrict__ W0p, float* __restrict__ W1p) {
    int i = blockIdx.x * 256 + threadIdx.x;
    if (i < DIN * HPAD) {
        int d = i / HPAD, h = i - d * HPAD;
        W0p[i] = (h < HID) ? W0[(DST + d) * HID + h] : 0.f;
    }
    if (i < HPAD) W1p[i] = (i < HID) ? W1[i] : 0.f;
}

// sp[b][h] = b0[h] + state[b] . W0[:75,h]   (padded to 80)
__global__ __launch_bounds__(128) void k_statepre(
    const float* __restrict__ state, const float* __restrict__ W0,
    const float* __restrict__ b0, float* __restrict__ sp) {
    int b = blockIdx.x;
    int h = threadIdx.x;
    if (h < HPAD) {
        float acc = 0.f;
        if (h < HID) {
            acc = b0[h];
            #pragma unroll 5
            for (int k = 0; k < DST; ++k)
                acc = fmaf(state[b * DST + k], W0[k * HID + h], acc);
        }
        sp[b * HPAD + h] = acc;
    }
}

// 256 threads = 4 waves; block owns 64 rows (lane = row). Wave w owns
// h-slice [w*20, w*20+20). Per-wave weight slice 150*20*4B = 12KB <= K$.
// x staged in LDS in two 75-col chunks (pad 77 -> odd stride, conflict-free).
// Only a 64-float scalar s per wave crosses waves (via LDS).
#define CW2  75
#define XPAD 77
__global__ __launch_bounds__(256, 8) void k_score(
    const float* __restrict__ in, const unsigned char* __restrict__ maskB,
    const float* __restrict__ W0p, const float* __restrict__ W1p,
    const float* __restrict__ b1, const float* __restrict__ sp,
    float* __restrict__ s1out) {
    __shared__ float xs[64 * XPAD];      // 19.7 KB
    int blk  = blockIdx.x;               // 2048 blocks
    int b    = blk >> 6;
    int l0   = (blk & 63) * 64;
    int tid  = threadIdx.x;
    int w    = tid >> 6;
    int lane = tid & 63;
    int hlo  = w * 20;

    const float* src = in + (size_t)(b * L_ + l0) * DIN;

    float pre[20];
    #pragma unroll
    for (int h = 0; h < 20; ++h) pre[h] = sp[b * HPAD + hlo + h];

    for (int c = 0; c < 2; ++c) {
        __syncthreads();                 // prev chunk consumed
        for (int i = tid; i < 64 * CW2; i += 256) {
            int r = i / CW2;
            int d = i - r * CW2;
            xs[r * XPAD + d] = src[r * DIN + c * CW2 + d];
        }
        __syncthreads();
        #pragma unroll 3
        for (int dj = 0; dj < CW2; ++dj) {
            float x = xs[lane * XPAD + dj];
            const float* wr = W0p + (c * CW2 + dj) * HPAD + hlo;  // uniform
            #pragma unroll
            for (int h = 0; h < 20; ++h) pre[h] = fmaf(x, wr[h], pre[h]);
        }
    }

    float sw = 0.f;
    #pragma unroll
    for (int h = 0; h < 20; ++h) {
        float p  = pre[h];
        float e  = __expf(-2.f * fabsf(p));
        float th = (1.f - e) / (1.f + e);          // tanh(|p|)
        sw = fmaf(copysignf(th, p), W1p[hlo + h], sw);
    }

    __syncthreads();                     // xs dead, reuse as s-reduce buffer
    xs[w * 64 + lane] = sw;
    __syncthreads();

    if (w == 0) {
        float s = xs[lane] + xs[64 + lane] + xs[128 + lane] + xs[192 + lane]
                + b1[0];
        // Mask dtype autodetect (validated r4): int32 -> bytes 4i+1 always 0.
        unsigned char probe = maskB[lane * 4 + 1];
        bool isI32 = __all(probe == 0);
        int l = l0 + lane;
        bool mv = isI32 ? (((const int*)maskB)[b * L_ + l] != 0)
                        : (maskB[b * L_ + l] != 0);
        s1out[b * L_ + l] = s - (mv ? 0.f : INF30);
    }
}

// Per-b max + sum(exp) over L, 1024 threads
__global__ __launch_bounds__(1024) void k_stats(
    const float* __restrict__ s1, float* __restrict__ mOut,
    float* __restrict__ invOut) {
    int b = blockIdx.x;
    int tid = threadIdx.x;
    int wid = tid >> 6;
    const float* row = s1 + b * L_;
    __shared__ float red[16];
    __shared__ float mfin;

    float m = -INFINITY;
    for (int i = tid; i < L_; i += 1024) m = fmaxf(m, row[i]);
    #pragma unroll
    for (int off = 32; off; off >>= 1) m = fmaxf(m, __shfl_down(m, off, 64));
    if ((tid & 63) == 0) red[wid] = m;
    __syncthreads();
    if (tid == 0) {
        float mm = red[0];
        for (int j = 1; j < 16; ++j) mm = fmaxf(mm, red[j]);
        mfin = mm;
    }
    __syncthreads();
    m = mfin;

    float sum = 0.f;
    for (int i = tid; i < L_; i += 1024) sum += __expf(row[i] - m);
    #pragma unroll
    for (int off = 32; off; off >>= 1) sum += __shfl_down(sum, off, 64);
    __syncthreads();
    if ((tid & 63) == 0) red[wid] = sum;
    __syncthreads();
    if (tid == 0) {
        float ss = 0.f;
        for (int j = 0; j < 16; ++j) ss += red[j];
        mOut[b]   = m;
        invOut[b] = 1.f / ss;
    }
}

// res[b][d] += sum_{l in chunk} softmax_w(l) * in[b][l][d]
#define CHUNK 64
__global__ __launch_bounds__(192) void k_weighted(
    const float* __restrict__ in, const float* __restrict__ s1,
    const float* __restrict__ mIn, const float* __restrict__ invIn,
    float* __restrict__ res) {
    int b   = blockIdx.y;
    int l0  = blockIdx.x * CHUNK;
    int tid = threadIdx.x;
    __shared__ float w[CHUNK];
    float m = mIn[b], inv = invIn[b];
    if (tid < CHUNK)
        w[tid] = __expf(s1[b * L_ + l0 + tid] - m) * inv;
    __syncthreads();
    if (tid < DIN) {
        float acc = 0.f;
        const float* p = in + (size_t)(b * L_ + l0) * DIN + tid;
        #pragma unroll 8
        for (int i = 0; i < CHUNK; ++i) acc = fmaf(w[i], p[i * DIN], acc);
        atomicAdd(&res[b * DIN + tid], acc);
    }
}

extern "C" void kernel_launch(void* const* d_in, const int* in_sizes, int n_in,
                              void* d_out, int out_size, void* d_ws, size_t ws_size,
                              hipStream_t stream) {
    const float*         inputs = (const float*)d_in[0];
    const float*         state  = (const float*)d_in[1];
    const unsigned char* cmask  = (const unsigned char*)d_in[2];
    const float*         W0     = (const float*)d_in[3];
    const float*         b0     = (const float*)d_in[4];
    const float*         W1     = (const float*)d_in[5];
    const float*         b1     = (const float*)d_in[6];

    float* res   = (float*)d_out;             // B*1*DIN = 4800
    float* s1    = (float*)d_out + B_ * DIN;  // B*L
    float* wsf   = (float*)d_ws;
    float* W0p   = wsf;                       // 12000
    float* W1p   = W0p + DIN * HPAD;          // 80
    float* sp    = W1p + HPAD;                // 2560
    float* mBuf  = sp + B_ * HPAD;            // 32
    float* invB  = mBuf + B_;                 // 32

    k_zero<<<(B_ * DIN + 255) / 256, 256, 0, stream>>>(res, B_ * DIN);
    k_prep<<<(DIN * HPAD + 255) / 256, 256, 0, stream>>>(W0, W1, W0p, W1p);
    k_statepre<<<B_, 128, 0, stream>>>(state, W0, b0, sp);
    k_score<<<B_ * L_ / 64, 256, 0, stream>>>(inputs, cmask, W0p, W1p, b1, sp, s1);
    k_stats<<<B_, 1024, 0, stream>>>(s1, mBuf, invB);
    dim3 gridW(L_ / CHUNK, B_);
    k_weighted<<<gridW, 192, 0, stream>>>(inputs, s1, mBuf, invB, res);
}

// Round 7
// 196.413 us; speedup vs baseline: 1.6529x; 1.6529x over previous
//
#include <hip/hip_runtime.h>

#define B_    32
#define L_    4096
#define DIN   150
#define DST   75
#define HID   75
#define HPAD  80
#define INF30 1e30f
#define SPART 152   // per-block partial stride: t[150], z, m

// ws: W0p[150*80], W1p[80], sp[32*80], part[2048*152]

__device__ __forceinline__ float tanh_fast(float p) {
    float e = __expf(-2.f * fabsf(p));
    float t = (1.f - e) / (1.f + e);
    return copysignf(t, p);
}

__global__ __launch_bounds__(256) void k_prep(
    const float* __restrict__ W0, const float* __restrict__ W1,
    float* __restrict__ W0p, float* __restrict__ W1p) {
    int i = blockIdx.x * 256 + threadIdx.x;
    if (i < DIN * HPAD) {
        int d = i / HPAD, h = i - d * HPAD;
        W0p[i] = (h < HID) ? W0[(DST + d) * HID + h] : 0.f;
    }
    if (i < HPAD) W1p[i] = (i < HID) ? W1[i] : 0.f;
}

__global__ __launch_bounds__(128) void k_statepre(
    const float* __restrict__ state, const float* __restrict__ W0,
    const float* __restrict__ b0, float* __restrict__ sp) {
    int b = blockIdx.x;
    int h = threadIdx.x;
    if (h < HPAD) {
        float acc = 0.f;
        if (h < HID) {
            acc = b0[h];
            #pragma unroll 5
            for (int k = 0; k < DST; ++k)
                acc = fmaf(state[b * DST + k], W0[k * HID + h], acc);
        }
        sp[b * HPAD + h] = acc;
    }
}

// Fused: per-block (64 rows) scorer GEMM + s1 + local softmax partials.
// XT[k][r] stored XOR-swizzled: phys = k*64 + ((r/4 ^ (k&15))*4) + r%4.
// GEMM reads (lanes=row-chunks, k uniform) and phase-C reads (lanes=k,
// row-chunk uniform) are both ~conflict-free under this swizzle.
__global__ __launch_bounds__(256, 4) void k_main(
    const float* __restrict__ in, const unsigned char* __restrict__ maskB,
    const float* __restrict__ W0p, const float* __restrict__ W1p,
    const float* __restrict__ b1, const float* __restrict__ sp,
    float* __restrict__ s1out, float* __restrict__ part) {
    __shared__ __align__(16) float XT[DIN * 64];   // 38400 B
    __shared__ __align__(16) float sred2[4 * 64];  // per-wave row partials
    __shared__ __align__(16) float wvals[64];

    int blk = blockIdx.x, tid = threadIdx.x;
    int b = blk >> 6, l0 = (blk & 63) << 6;
    const float4* src4 = (const float4*)(in + (size_t)(b * L_ + l0) * DIN);

    // ---- stage x -> XT (transposed + swizzled). 9600 floats contiguous.
    #pragma unroll
    for (int p = 0; p < 10; ++p) {
        int i4 = p * 256 + tid;
        if (i4 < 2400) {
            float4 v = src4[i4];
            int idx = i4 << 2;
            float vals[4] = {v.x, v.y, v.z, v.w};
            #pragma unroll
            for (int e = 0; e < 4; ++e) {
                int id = idx + e;
                int r = id / DIN;
                int k = id - r * DIN;
                XT[(k << 6) + (((r >> 2) ^ (k & 15)) << 2) + (r & 3)] = vals[e];
            }
        }
    }
    __syncthreads();

    // ---- GEMM: thread (rg,cg) = rows 4rg..4rg+3 x cols {4cg..4cg+3, 64+cg}
    int rg = tid & 15, cg = tid >> 4;
    float acc[4][5];
    {
        float s0 = sp[b * HPAD + (cg << 2) + 0];
        float s1_ = sp[b * HPAD + (cg << 2) + 1];
        float s2 = sp[b * HPAD + (cg << 2) + 2];
        float s3 = sp[b * HPAD + (cg << 2) + 3];
        float s4 = sp[b * HPAD + 64 + cg];
        #pragma unroll
        for (int j = 0; j < 4; ++j) {
            acc[j][0] = s0; acc[j][1] = s1_; acc[j][2] = s2;
            acc[j][3] = s3; acc[j][4] = s4;
        }
    }
    const float* wb4 = W0p + (cg << 2);
    const float* wb1 = W0p + 64 + cg;
    #pragma unroll 6
    for (int k = 0; k < DIN; ++k) {
        float4 xv = *(const float4*)&XT[(k << 6) + ((rg ^ (k & 15)) << 2)];
        float4 wv = *(const float4*)&wb4[k * HPAD];
        float  w4 = wb1[k * HPAD];
        float xj[4] = {xv.x, xv.y, xv.z, xv.w};
        #pragma unroll
        for (int j = 0; j < 4; ++j) {
            acc[j][0] = fmaf(xj[j], wv.x, acc[j][0]);
            acc[j][1] = fmaf(xj[j], wv.y, acc[j][1]);
            acc[j][2] = fmaf(xj[j], wv.z, acc[j][2]);
            acc[j][3] = fmaf(xj[j], wv.w, acc[j][3]);
            acc[j][4] = fmaf(xj[j], w4,   acc[j][4]);
        }
    }

    // ---- tanh + W1 contract; reduce across cg (xor16/32 = same wave)
    float w1a = W1p[(cg << 2) + 0], w1b = W1p[(cg << 2) + 1];
    float w1c = W1p[(cg << 2) + 2], w1d = W1p[(cg << 2) + 3];
    float w1e = W1p[64 + cg];
    int wv_ = tid >> 6, lane = tid & 63;
    float spart[4];
    #pragma unroll
    for (int j = 0; j < 4; ++j) {
        float s = 0.f;
        s = fmaf(tanh_fast(acc[j][0]), w1a, s);
        s = fmaf(tanh_fast(acc[j][1]), w1b, s);
        s = fmaf(tanh_fast(acc[j][2]), w1c, s);
        s = fmaf(tanh_fast(acc[j][3]), w1d, s);
        s = fmaf(tanh_fast(acc[j][4]), w1e, s);
        s += __shfl_xor(s, 16, 64);
        s += __shfl_xor(s, 32, 64);
        spart[j] = s;
    }
    if (lane < 16) {            // cg-local 0 lanes hold the 4-cg sums
        #pragma unroll
        for (int j = 0; j < 4; ++j)
            sred2[(wv_ << 6) + (lane << 2) + j] = spart[j];
    }
    __syncthreads();

    // ---- final s, mask, s1 write, local softmax stats (wave 0)
    if (tid < 64) {
        float s = b1[0] + sred2[tid] + sred2[64 + tid]
                + sred2[128 + tid] + sred2[192 + tid];
        unsigned char probe = maskB[tid * 4 + 1];   // dtype autodetect
        bool isI32 = __all(probe == 0);
        int l = l0 + tid;
        bool mv = isI32 ? (((const int*)maskB)[b * L_ + l] != 0)
                        : (maskB[b * L_ + l] != 0);
        float s1v = s - (mv ? 0.f : INF30);
        s1out[b * L_ + l] = s1v;
        float mx = s1v;
        #pragma unroll
        for (int off = 1; off < 64; off <<= 1)
            mx = fmaxf(mx, __shfl_xor(mx, off, 64));
        float wexp = __expf(s1v - mx);
        wvals[tid] = wexp;
        float z = wexp;
        #pragma unroll
        for (int off = 1; off < 64; off <<= 1) z += __shfl_xor(z, off, 64);
        if (tid == 0) {
            part[(size_t)blk * SPART + 150] = z;
            part[(size_t)blk * SPART + 151] = mx;
        }
    }
    __syncthreads();

    // ---- phase C: t[d] = sum_l wvals[l] * x[l][d] from resident XT
    if (tid < DIN) {
        float t0 = 0.f, t1 = 0.f, t2 = 0.f, t3 = 0.f;
        int dd = tid & 15;
        #pragma unroll
        for (int lq = 0; lq < 16; ++lq) {
            float4 xt = *(const float4*)&XT[(tid << 6) + ((lq ^ dd) << 2)];
            float4 wq = *(const float4*)&wvals[lq << 2];
            t0 = fmaf(xt.x, wq.x, t0);
            t1 = fmaf(xt.y, wq.y, t1);
            t2 = fmaf(xt.z, wq.z, t2);
            t3 = fmaf(xt.w, wq.w, t3);
        }
        part[(size_t)blk * SPART + tid] = (t0 + t1) + (t2 + t3);
    }
}

// res[b][d] = sum_c t_c[d] e^{m_c-M} / sum_c z_c e^{m_c-M}
__global__ __launch_bounds__(192) void k_combine(
    const float* __restrict__ part, float* __restrict__ res) {
    int b = blockIdx.x, tid = threadIdx.x;
    float M = -INFINITY;
    #pragma unroll 8
    for (int c = 0; c < 64; ++c)
        M = fmaxf(M, part[(size_t)((b << 6) + c) * SPART + 151]);
    if (tid < DIN) {
        float ts = 0.f, zs = 0.f;
        #pragma unroll 4
        for (int c = 0; c < 64; ++c) {
            const float* pc = part + (size_t)((b << 6) + c) * SPART;
            float e = __expf(pc[151] - M);
            ts = fmaf(pc[tid], e, ts);
            zs = fmaf(pc[150], e, zs);
        }
        res[b * DIN + tid] = ts / zs;
    }
}

extern "C" void kernel_launch(void* const* d_in, const int* in_sizes, int n_in,
                              void* d_out, int out_size, void* d_ws, size_t ws_size,
                              hipStream_t stream) {
    const float*         inputs = (const float*)d_in[0];
    const float*         state  = (const float*)d_in[1];
    const unsigned char* cmask  = (const unsigned char*)d_in[2];
    const float*         W0     = (const float*)d_in[3];
    const float*         b0     = (const float*)d_in[4];
    const float*         W1     = (const float*)d_in[5];
    const float*         b1     = (const float*)d_in[6];

    float* res  = (float*)d_out;             // B*1*DIN
    float* s1   = (float*)d_out + B_ * DIN;  // B*L
    float* wsf  = (float*)d_ws;
    float* W0p  = wsf;                       // 12000
    float* W1p  = W0p + DIN * HPAD;          // 80
    float* sp   = W1p + HPAD;                // 2560
    float* part = sp + B_ * HPAD;            // 2048*152

    k_prep<<<(DIN * HPAD + 255) / 256, 256, 0, stream>>>(W0, W1, W0p, W1p);
    k_statepre<<<B_, 128, 0, stream>>>(state, W0, b0, sp);
    k_main<<<B_ * L_ / 64, 256, 0, stream>>>(inputs, cmask, W0p, W1p, b1, sp,
                                             s1, part);
    k_combine<<<B_, 192, 0, stream>>>(part, res);
}